// Round 3
// baseline (105.938 us; speedup 1.0000x reference)
//
#include <hip/hip_runtime.h>

// ActorCriticMSECriterionAIC: masked MSE criterion (fused single kernel).
// Inputs: seq [B,S] int32, value [B,S] f32, reward [B,S] f32 (B=65536, S=256).
// Outputs (3 f32): loss = sum(diff^2*mask)/sum(mask), mean(reward-value), mean(reward).
// mask[b,j] = 1 iff no zero among seq[b,0..j-1]  (count = first_zero+1, S if none).
//
// R2 counters: VGPR=28 (loads serialized, ~3 in flight), occupancy 66%
// (4096 blocks over ~2048 slots = 2 rounds + tail), second kernel+launch
// overhead ~5us. R3:
//  - nb=2048 (one resident round), chunked rows, unconditional paired loads
//    into explicit locals (6 x 16B in flight, offsets folded into imm).
//  - per-lane mask via ballot & lanemask_lt only (no ffs, no shfl broadcast,
//    no lane==0 divergence); sv dropped (sum(r-v) from diffs directly).
//  - finalize fused via last-block atomic ticket (threadfence protocol),
//    removing the 2nd dispatch.

__global__ __launch_bounds__(256) void ac_mse_fused(
    const int* __restrict__ seq,
    const float* __restrict__ value,
    const float* __restrict__ reward,
    double* __restrict__ part,       // SoA [4][nb]
    unsigned* __restrict__ ticket,   // zeroed by host memset each launch
    float* __restrict__ out,
    int B, int nb, double inv_n) {

    const int S = 256;
    const int lane = threadIdx.x & 63;
    const int wv = threadIdx.x >> 6;
    const int wave = blockIdx.x * 4 + wv;
    const int total_waves = nb * 4;

    // chunked contiguous row range for this wave (exact split, no tail checks
    // in the hot loop; B=65536 / 8192 waves = 8 rows each)
    const int rpw = B / total_waves;
    const int rem = B - rpw * total_waves;
    const int row0 = wave * rpw + (wave < rem ? wave : rem);
    const int nrows = rpw + (wave < rem ? 1 : 0);

    double acc_sq = 0.0, acc_sd = 0.0, acc_sr = 0.0;
    int cnt = 0;
    const unsigned long long lmlt = (1ull << lane) - 1ull;  // lanes below me

    const size_t elem0 = (size_t)row0 * S + (size_t)(lane * 4);
    const int*   sp = seq + elem0;
    const float* vp = value + elem0;
    const float* rp = reward + elem0;

    auto row = [&](const int4 s, const float4 v, const float4 r) {
        int p = 4;                       // first zero pos within my 4 (4=none)
        if (s.w == 0) p = 3;
        if (s.z == 0) p = 2;
        if (s.y == 0) p = 1;
        if (s.x == 0) p = 0;
        const unsigned long long zm = __ballot(p < 4);
        // my masked-element count: 0 if a zero occurs in an earlier lane,
        // else p+1 if my chunk has the first zero, else all 4.
        const int m = ((zm & lmlt) == 0) ? ((p < 4) ? p + 1 : 4) : 0;

        const float d0 = r.x - v.x;
        const float d1 = r.y - v.y;
        const float d2 = r.z - v.z;
        const float d3 = r.w - v.w;
        float lsq = 0.0f;
        if (m > 0) lsq += d0 * d0;
        if (m > 1) lsq += d1 * d1;
        if (m > 2) lsq += d2 * d2;
        if (m > 3) lsq += d3 * d3;

        cnt += m;
        acc_sq += (double)lsq;
        acc_sd += (double)((d0 + d1) + (d2 + d3));
        acc_sr += (double)((r.x + r.y) + (r.z + r.w));
    };

    int k = 0;
    for (; k + 2 <= nrows; k += 2) {
        // all 6 loads issued before any use; +S offsets fold to imm (+1024B)
        const int4   s0 = *reinterpret_cast<const int4*>(sp);
        const int4   s1 = *reinterpret_cast<const int4*>(sp + S);
        const float4 v0 = *reinterpret_cast<const float4*>(vp);
        const float4 v1 = *reinterpret_cast<const float4*>(vp + S);
        const float4 r0 = *reinterpret_cast<const float4*>(rp);
        const float4 r1 = *reinterpret_cast<const float4*>(rp + S);
        sp += 2 * S; vp += 2 * S; rp += 2 * S;
        row(s0, v0, r0);
        row(s1, v1, r1);
    }
    if (k < nrows) {
        const int4   s0 = *reinterpret_cast<const int4*>(sp);
        const float4 v0 = *reinterpret_cast<const float4*>(vp);
        const float4 r0 = *reinterpret_cast<const float4*>(rp);
        row(s0, v0, r0);
    }

    // wave reduction (4 quantities)
    double acc_cnt = (double)cnt;
    #pragma unroll
    for (int off = 32; off > 0; off >>= 1) {
        acc_sq  += __shfl_down(acc_sq,  off);
        acc_cnt += __shfl_down(acc_cnt, off);
        acc_sd  += __shfl_down(acc_sd,  off);
        acc_sr  += __shfl_down(acc_sr,  off);
    }

    __shared__ double sm[4][4];
    __shared__ unsigned is_last;
    if (lane == 0) {
        sm[0][wv] = acc_sq;
        sm[1][wv] = acc_cnt;
        sm[2][wv] = acc_sd;
        sm[3][wv] = acc_sr;
    }
    __syncthreads();
    if (threadIdx.x == 0) {
        part[0 * (size_t)nb + blockIdx.x] = sm[0][0] + sm[0][1] + sm[0][2] + sm[0][3];
        part[1 * (size_t)nb + blockIdx.x] = sm[1][0] + sm[1][1] + sm[1][2] + sm[1][3];
        part[2 * (size_t)nb + blockIdx.x] = sm[2][0] + sm[2][1] + sm[2][2] + sm[2][3];
        part[3 * (size_t)nb + blockIdx.x] = sm[3][0] + sm[3][1] + sm[3][2] + sm[3][3];
        __threadfence();                         // publish partials device-wide
        const unsigned t = atomicAdd(ticket, 1u);
        is_last = (t == (unsigned)(nb - 1)) ? 1u : 0u;
    }
    __syncthreads();

    if (is_last) {
        // last block reduces all partials: wave c handles component c
        __threadfence();                         // acquire published partials
        const double* p = part + (size_t)wv * nb;
        double a0 = 0, a1 = 0, a2 = 0, a3 = 0;
        int b = lane;
        for (; b + 192 < nb; b += 256) {
            a0 += p[b]; a1 += p[b + 64]; a2 += p[b + 128]; a3 += p[b + 192];
        }
        for (; b < nb; b += 64) a0 += p[b];
        double a = (a0 + a1) + (a2 + a3);
        #pragma unroll
        for (int off = 32; off > 0; off >>= 1) a += __shfl_down(a, off);

        __shared__ double fin[4];
        if (lane == 0) fin[wv] = a;
        __syncthreads();
        if (threadIdx.x == 0) {
            out[0] = (float)(fin[0] / fin[1]);   // loss
            out[1] = (float)(fin[2] * inv_n);    // mean(reward - value)
            out[2] = (float)(fin[3] * inv_n);    // mean(reward)
        }
    }
}

extern "C" void kernel_launch(void* const* d_in, const int* in_sizes, int n_in,
                              void* d_out, int out_size, void* d_ws, size_t ws_size,
                              hipStream_t stream) {
    const int*   seq    = (const int*)d_in[0];
    const float* value  = (const float*)d_in[1];
    const float* reward = (const float*)d_in[2];
    float* out = (float*)d_out;

    const int S = 256;
    const long long total = (long long)in_sizes[0];
    const int B = (int)(total / S);

    // ws layout: [0..15] ticket (16B pad), then 4*nb doubles of partials
    unsigned* ticket = (unsigned*)d_ws;
    double*   part   = (double*)((char*)d_ws + 16);

    int nb = 2048;   // one full resident round (256 CU x 8 waves / 4 per block)
    const size_t need = 16 + (size_t)nb * 4 * sizeof(double);
    if (ws_size < need) nb = (int)((ws_size - 16) / (4 * sizeof(double)));

    hipMemsetAsync(ticket, 0, sizeof(unsigned), stream);
    ac_mse_fused<<<nb, 256, 0, stream>>>(seq, value, reward, part, ticket, out,
                                         B, nb, 1.0 / (double)total);
}

// Round 4
// 99.470 us; speedup vs baseline: 1.0650x; 1.0650x over previous
//
#include <hip/hip_runtime.h>

// ActorCriticMSECriterionAIC: masked MSE criterion (fused single kernel).
// Inputs: seq [B,S] int32, value [B,S] f32, reward [B,S] f32 (B=65536, S=256).
// Outputs (3 f32): loss = sum(diff^2*mask)/sum(mask), mean(reward-value), mean(reward).
// mask[b,j] = 1 iff no zero among seq[b,0..j-1]  (count = first_zero+1, S if none).
//
// R3 post-mortem: chunked row assignment collapsed DRAM BW (0.58 TB/s, every
// concurrent access 8KB apart -> page-miss storm). R4:
//  - INTERLEAVED rows restored (wave w handles rows w, w+T, ...): consecutive
//    waves read consecutive rows -> sequential device-wide sweep (R2's 1.45TB/s).
//  - depth-1 software pipeline: next row's 3x16B loads issued into named regs
//    before processing current (R2/R3 had VGPR=28 = ~1 row in flight).
//  - fused finalize via ticket kept; pow2-nb "& (nb-1)" trick makes it correct
//    from ANY initial ticket value -> no memset dispatch at all.

__global__ __launch_bounds__(256) void ac_mse_fused(
    const int* __restrict__ seq,
    const float* __restrict__ value,
    const float* __restrict__ reward,
    double* __restrict__ part,       // SoA [4][nb]
    unsigned* __restrict__ ticket,   // monotone; pow2 trick, no reset needed
    float* __restrict__ out,
    int B, int nb, double inv_n) {

    const int S = 256;
    const int lane = threadIdx.x & 63;
    const int wv = threadIdx.x >> 6;
    const int wave = blockIdx.x * 4 + wv;
    const int T = nb * 4;                       // total waves

    double acc_sq = 0.0, acc_sd = 0.0, acc_sr = 0.0;
    int cnt = 0;
    const unsigned long long lmlt = (1ull << lane) - 1ull;

    const size_t step = (size_t)T * S;          // elements between my rows
    const size_t e0 = (size_t)wave * S + (size_t)(lane * 4);
    const int*   sp = seq + e0;
    const float* vp = value + e0;
    const float* rp = reward + e0;

    auto process = [&](const int4 s, const float4 v, const float4 r) {
        int p = 4;                              // first zero in my 4 (4=none)
        if (s.w == 0) p = 3;
        if (s.z == 0) p = 2;
        if (s.y == 0) p = 1;
        if (s.x == 0) p = 0;
        const unsigned long long zm = __ballot(p < 4);
        const int m = ((zm & lmlt) == 0) ? ((p < 4) ? p + 1 : 4) : 0;

        const float d0 = r.x - v.x;
        const float d1 = r.y - v.y;
        const float d2 = r.z - v.z;
        const float d3 = r.w - v.w;
        float lsq = 0.0f;
        if (m > 0) lsq += d0 * d0;
        if (m > 1) lsq += d1 * d1;
        if (m > 2) lsq += d2 * d2;
        if (m > 3) lsq += d3 * d3;

        cnt += m;
        acc_sq += (double)lsq;
        acc_sd += (double)((d0 + d1) + (d2 + d3));
        acc_sr += (double)((r.x + r.y) + (r.z + r.w));
    };

    const int niter = (wave < B) ? ((B - wave + T - 1) / T) : 0;  // 8 when B=65536
    if (niter > 0) {
        // prologue: load row 0
        int4   cs = *reinterpret_cast<const int4*>(sp);
        float4 cv = *reinterpret_cast<const float4*>(vp);
        float4 cr = *reinterpret_cast<const float4*>(rp);
        for (int k = 0; k < niter; ++k) {
            int4 ns; float4 nv, nr;
            const bool more = (k + 1 < niter);  // wave-uniform
            if (more) {                          // issue next-row loads FIRST
                sp += step; vp += step; rp += step;
                ns = *reinterpret_cast<const int4*>(sp);
                nv = *reinterpret_cast<const float4*>(vp);
                nr = *reinterpret_cast<const float4*>(rp);
            }
            process(cs, cv, cr);                 // overlaps with ns/nv/nr fill
            cs = ns; cv = nv; cr = nr;
        }
    }

    // wave reduction (4 quantities)
    double acc_cnt = (double)cnt;
    #pragma unroll
    for (int off = 32; off > 0; off >>= 1) {
        acc_sq  += __shfl_down(acc_sq,  off);
        acc_cnt += __shfl_down(acc_cnt, off);
        acc_sd  += __shfl_down(acc_sd,  off);
        acc_sr  += __shfl_down(acc_sr,  off);
    }

    __shared__ double sm[4][4];
    __shared__ unsigned is_last;
    if (lane == 0) {
        sm[0][wv] = acc_sq;
        sm[1][wv] = acc_cnt;
        sm[2][wv] = acc_sd;
        sm[3][wv] = acc_sr;
    }
    __syncthreads();
    if (threadIdx.x == 0) {
        part[0 * (size_t)nb + blockIdx.x] = sm[0][0] + sm[0][1] + sm[0][2] + sm[0][3];
        part[1 * (size_t)nb + blockIdx.x] = sm[1][0] + sm[1][1] + sm[1][2] + sm[1][3];
        part[2 * (size_t)nb + blockIdx.x] = sm[2][0] + sm[2][1] + sm[2][2] + sm[2][3];
        part[3 * (size_t)nb + blockIdx.x] = sm[3][0] + sm[3][1] + sm[3][2] + sm[3][3];
        __threadfence();                        // publish partials
        const unsigned t = atomicAdd(ticket, 1u) + 1u;
        // nb is pow2: exactly one block per launch sees remainder 0,
        // regardless of the ticket's initial (poisoned) value.
        is_last = ((t & (unsigned)(nb - 1)) == 0u) ? 1u : 0u;
    }
    __syncthreads();

    if (is_last) {
        __threadfence();
        const double* p = part + (size_t)wv * nb;   // wave c -> component c
        double a0 = 0, a1 = 0, a2 = 0, a3 = 0;
        int b = lane;
        for (; b + 192 < nb; b += 256) {
            a0 += p[b]; a1 += p[b + 64]; a2 += p[b + 128]; a3 += p[b + 192];
        }
        for (; b < nb; b += 64) a0 += p[b];
        double a = (a0 + a1) + (a2 + a3);
        #pragma unroll
        for (int off = 32; off > 0; off >>= 1) a += __shfl_down(a, off);

        __shared__ double fin[4];
        if (lane == 0) fin[wv] = a;
        __syncthreads();
        if (threadIdx.x == 0) {
            out[0] = (float)(fin[0] / fin[1]);   // loss
            out[1] = (float)(fin[2] * inv_n);    // mean(reward - value)
            out[2] = (float)(fin[3] * inv_n);    // mean(reward)
        }
    }
}

extern "C" void kernel_launch(void* const* d_in, const int* in_sizes, int n_in,
                              void* d_out, int out_size, void* d_ws, size_t ws_size,
                              hipStream_t stream) {
    const int*   seq    = (const int*)d_in[0];
    const float* value  = (const float*)d_in[1];
    const float* reward = (const float*)d_in[2];
    float* out = (float*)d_out;

    const int S = 256;
    const long long total = (long long)in_sizes[0];
    const int B = (int)(total / S);

    // ws layout: [0..15] ticket (16B pad), then 4*nb doubles of partials
    unsigned* ticket = (unsigned*)d_ws;
    double*   part   = (double*)((char*)d_ws + 16);

    int nb = 2048;   // one resident round; MUST stay a power of two (ticket trick)
    while ((size_t)nb * 4 * sizeof(double) + 16 > ws_size && nb > 1) nb >>= 1;

    ac_mse_fused<<<nb, 256, 0, stream>>>(seq, value, reward, part, ticket, out,
                                         B, nb, 1.0 / (double)total);
}

// Round 5
// 39.990 us; speedup vs baseline: 2.6491x; 2.4873x over previous
//
#include <hip/hip_runtime.h>

// ActorCriticMSECriterionAIC: masked MSE criterion.
// Inputs: seq [B,S] int32, value [B,S] f32, reward [B,S] f32 (B=65536, S=256).
// Outputs (3 f32): loss = sum(diff^2*mask)/sum(mask), mean(reward-value), mean(reward).
// mask[b,j] = 1 iff no zero among seq[b,0..j-1]  (count = first_zero+1, S if none).
//
// R4 post-mortem: ticket-fused finalize is RACY across XCDs (absmax 3.9e-3;
// plain loads after threadfence are not a device-scope acquire over
// non-coherent per-XCD L2s) and implicated in the 99-106us regressions.
// The depth-1 pipeline collapsed (VGPR 24: compiler serialized loads).
// R5 = R2's proven 2-kernel structure (42us) + two targeted changes:
//  - 4-row straight-line unroll: 12 x 16B loads in one basic block, no
//    conditionals (B/total_waves = 8 exactly -> no tail at bench shape).
//  - __launch_bounds__(256, 2): lift VGPR cap to 256 so the scheduler stops
//    pressure-sinking the loads (every prior round: VGPR<=28, ~1 row in
//    flight). Occupancy drops; MLP per wave is what we need instead.

__global__ __launch_bounds__(256, 2) void ac_mse_reduce(
    const int* __restrict__ seq,
    const float* __restrict__ value,
    const float* __restrict__ reward,
    double* __restrict__ part,       // SoA [4][nb]
    int B, int nb) {

    const int S = 256;
    const int lane = threadIdx.x & 63;
    const int wv = threadIdx.x >> 6;
    const int wave = blockIdx.x * 4 + wv;
    const int T = nb * 4;                       // total waves

    double acc_sq = 0.0, acc_sd = 0.0, acc_sr = 0.0;
    int cnt = 0;
    const unsigned long long lmlt = (1ull << lane) - 1ull;

    const size_t step = (size_t)T * S;          // elements between my rows
    const size_t e0 = (size_t)wave * S + (size_t)(lane * 4);
    const int*   sp = seq + e0;
    const float* vp = value + e0;
    const float* rp = reward + e0;

    auto process = [&](const int4 s, const float4 v, const float4 r) {
        int p = 4;                              // first zero in my 4 (4=none)
        if (s.w == 0) p = 3;
        if (s.z == 0) p = 2;
        if (s.y == 0) p = 1;
        if (s.x == 0) p = 0;
        const unsigned long long zm = __ballot(p < 4);
        const int m = ((zm & lmlt) == 0) ? ((p < 4) ? p + 1 : 4) : 0;

        const float d0 = r.x - v.x;
        const float d1 = r.y - v.y;
        const float d2 = r.z - v.z;
        const float d3 = r.w - v.w;
        float lsq = 0.0f;
        if (m > 0) lsq += d0 * d0;
        if (m > 1) lsq += d1 * d1;
        if (m > 2) lsq += d2 * d2;
        if (m > 3) lsq += d3 * d3;

        cnt += m;
        acc_sq += (double)lsq;
        acc_sd += (double)((d0 + d1) + (d2 + d3));
        acc_sr += (double)((r.x + r.y) + (r.z + r.w));
    };

    const int niter = (wave < B) ? ((B - 1 - wave) / T + 1) : 0;   // 8 at bench shape
    int k = 0;
    // main: 4 rows per trip, all 12 loads issued straight-line before any use
    for (; k + 4 <= niter; k += 4) {
        const int4   s0 = *reinterpret_cast<const int4*>(sp);
        const int4   s1 = *reinterpret_cast<const int4*>(sp + step);
        const int4   s2 = *reinterpret_cast<const int4*>(sp + 2 * step);
        const int4   s3 = *reinterpret_cast<const int4*>(sp + 3 * step);
        const float4 v0 = *reinterpret_cast<const float4*>(vp);
        const float4 v1 = *reinterpret_cast<const float4*>(vp + step);
        const float4 v2 = *reinterpret_cast<const float4*>(vp + 2 * step);
        const float4 v3 = *reinterpret_cast<const float4*>(vp + 3 * step);
        const float4 r0 = *reinterpret_cast<const float4*>(rp);
        const float4 r1 = *reinterpret_cast<const float4*>(rp + step);
        const float4 r2 = *reinterpret_cast<const float4*>(rp + 2 * step);
        const float4 r3 = *reinterpret_cast<const float4*>(rp + 3 * step);
        sp += 4 * step; vp += 4 * step; rp += 4 * step;
        process(s0, v0, r0);
        process(s1, v1, r1);
        process(s2, v2, r2);
        process(s3, v3, r3);
    }
    for (; k < niter; ++k) {                    // generic-shape tail only
        const int4   s0 = *reinterpret_cast<const int4*>(sp);
        const float4 v0 = *reinterpret_cast<const float4*>(vp);
        const float4 r0 = *reinterpret_cast<const float4*>(rp);
        sp += step; vp += step; rp += step;
        process(s0, v0, r0);
    }

    // wave reduction (4 quantities)
    double acc_cnt = (double)cnt;
    #pragma unroll
    for (int off = 32; off > 0; off >>= 1) {
        acc_sq  += __shfl_down(acc_sq,  off);
        acc_cnt += __shfl_down(acc_cnt, off);
        acc_sd  += __shfl_down(acc_sd,  off);
        acc_sr  += __shfl_down(acc_sr,  off);
    }

    __shared__ double sm[4][4];
    if (lane == 0) {
        sm[0][wv] = acc_sq;
        sm[1][wv] = acc_cnt;
        sm[2][wv] = acc_sd;
        sm[3][wv] = acc_sr;
    }
    __syncthreads();
    if (threadIdx.x == 0) {
        part[0 * (size_t)nb + blockIdx.x] = sm[0][0] + sm[0][1] + sm[0][2] + sm[0][3];
        part[1 * (size_t)nb + blockIdx.x] = sm[1][0] + sm[1][1] + sm[1][2] + sm[1][3];
        part[2 * (size_t)nb + blockIdx.x] = sm[2][0] + sm[2][1] + sm[2][2] + sm[2][3];
        part[3 * (size_t)nb + blockIdx.x] = sm[3][0] + sm[3][1] + sm[3][2] + sm[3][3];
    }
}

// One block, 4 waves: wave c reduces component c over nb block-partials.
__global__ __launch_bounds__(256) void ac_mse_final(
    const double* __restrict__ part, float* __restrict__ out,
    int nb, double inv_n) {

    const int lane = threadIdx.x & 63;
    const int c = threadIdx.x >> 6;
    const double* p = part + (size_t)c * nb;

    double a0 = 0, a1 = 0, a2 = 0, a3 = 0;
    int b = lane;
    for (; b + 192 < nb; b += 256) {
        a0 += p[b]; a1 += p[b + 64]; a2 += p[b + 128]; a3 += p[b + 192];
    }
    for (; b < nb; b += 64) a0 += p[b];
    double a = (a0 + a1) + (a2 + a3);

    #pragma unroll
    for (int off = 32; off > 0; off >>= 1) a += __shfl_down(a, off);

    __shared__ double sm[4];
    if (lane == 0) sm[c] = a;
    __syncthreads();
    if (threadIdx.x == 0) {
        out[0] = (float)(sm[0] / sm[1]);            // loss
        out[1] = (float)(sm[2] * inv_n);            // mean(reward - value)
        out[2] = (float)(sm[3] * inv_n);            // mean(reward)
    }
}

extern "C" void kernel_launch(void* const* d_in, const int* in_sizes, int n_in,
                              void* d_out, int out_size, void* d_ws, size_t ws_size,
                              hipStream_t stream) {
    const int*   seq    = (const int*)d_in[0];
    const float* value  = (const float*)d_in[1];
    const float* reward = (const float*)d_in[2];
    float*  out = (float*)d_out;
    double* ws  = (double*)d_ws;

    const int S = 256;
    const long long total = (long long)in_sizes[0];
    const int B = (int)(total / S);

    int nb = 2048;   // 8192 waves -> 8 rows/wave (2 x 4-row trips, no tail)
    while ((size_t)nb * 4 * sizeof(double) > ws_size && nb > 1) nb >>= 1;

    ac_mse_reduce<<<nb, 256, 0, stream>>>(seq, value, reward, ws, B, nb);
    ac_mse_final<<<1, 256, 0, stream>>>(ws, out, nb, 1.0 / (double)total);
}

// Round 6
// 32.501 us; speedup vs baseline: 3.2595x; 1.2304x over previous
//
#include <hip/hip_runtime.h>

// ActorCriticMSECriterionAIC: masked MSE criterion.
// Inputs: seq [B,S] int32, value [B,S] f32, reward [B,S] f32 (B=65536, S=256).
// Outputs (3 f32): loss = sum(diff^2*mask)/sum(mask), mean(reward-value), mean(reward).
// mask[b,j] = 1 iff no zero among seq[b,0..j-1]  (count = first_zero+1, S if none).
//
// R5 post-mortem: 40us; VGPR stayed 28 (compiler sinks loads regardless) but
// MLP is NOT the limiter (24 waves/CU x 3 x 1KB >> Little's-law need). We are
// near the streaming ceiling FOR 201 MB. R6 cuts bytes instead:
//  - seq is only needed up to the first zero. Read it in 64-elem chunks
//    (1 dword/lane, perfectly coalesced 256B) with ballot early-exit:
//    P(no zero in 64) = 0.95^64 = 3.8% -> avg ~266B instead of 1024B per row.
//    Seq traffic 67MB -> ~17MB; total 201 -> ~152MB (-25%).
//  - value/reward stay full-row float4 (unmasked means need every element).
//  - proven 2-kernel structure, interleaved rows, 4-row unroll kept.

__global__ __launch_bounds__(256, 2) void ac_mse_reduce(
    const int* __restrict__ seq,
    const float* __restrict__ value,
    const float* __restrict__ reward,
    double* __restrict__ part,       // SoA [4][nb]
    int B, int nb) {

    const int S = 256;
    const int lane = threadIdx.x & 63;
    const int wv = threadIdx.x >> 6;
    const int wave = blockIdx.x * 4 + wv;
    const int T = nb * 4;                       // total waves

    double acc_sq = 0.0, acc_sd = 0.0, acc_sr = 0.0;
    int cnt = 0;

    const size_t step = (size_t)T * S;          // elements between my rows
    // seq: lane reads dword at (row, 64c + lane); v/r: float4 at (row, 4*lane)
    const int*   spl = seq + (size_t)wave * S + (size_t)lane;
    const float* vp  = value + (size_t)wave * S + (size_t)(lane * 4);
    const float* rp  = reward + (size_t)wave * S + (size_t)(lane * 4);

    // s0: my dword from seq elems [0..63]; sq: base of this row's seq (+lane)
    auto process = [&](int s0, const float4 v, const float4 r, const int* sq) {
        unsigned long long bal = __ballot(s0 == 0);
        int count;
        if (bal) {
            count = __ffsll(bal);               // first_zero + 1
        } else {
            count = S;
            // rare (3.8% of rows), wave-uniform chunk walk
            for (int c = 1; c < S / 64; ++c) {
                const int sc = sq[c * 64];      // sq already includes +lane
                const unsigned long long b2 = __ballot(sc == 0);
                if (b2) { count = c * 64 + (int)__ffsll(b2); break; }
            }
        }
        int m = count - 4 * lane;               // my masked-elem count (0..4)
        m = m < 0 ? 0 : (m > 4 ? 4 : m);

        const float d0 = r.x - v.x;
        const float d1 = r.y - v.y;
        const float d2 = r.z - v.z;
        const float d3 = r.w - v.w;
        float lsq = 0.0f;
        if (m > 0) lsq += d0 * d0;
        if (m > 1) lsq += d1 * d1;
        if (m > 2) lsq += d2 * d2;
        if (m > 3) lsq += d3 * d3;

        cnt += m;
        acc_sq += (double)lsq;
        acc_sd += (double)((d0 + d1) + (d2 + d3));
        acc_sr += (double)((r.x + r.y) + (r.z + r.w));
    };

    const int niter = (wave < B) ? ((B - 1 - wave) / T + 1) : 0;   // 8 at bench shape
    int k = 0;
    for (; k + 4 <= niter; k += 4) {
        // 12 loads issued straight-line (4 dword + 8 float4)
        const int    s0 = spl[0];
        const int    s1 = spl[step];
        const int    s2 = spl[2 * step];
        const int    s3 = spl[3 * step];
        const float4 v0 = *reinterpret_cast<const float4*>(vp);
        const float4 v1 = *reinterpret_cast<const float4*>(vp + step);
        const float4 v2 = *reinterpret_cast<const float4*>(vp + 2 * step);
        const float4 v3 = *reinterpret_cast<const float4*>(vp + 3 * step);
        const float4 r0 = *reinterpret_cast<const float4*>(rp);
        const float4 r1 = *reinterpret_cast<const float4*>(rp + step);
        const float4 r2 = *reinterpret_cast<const float4*>(rp + 2 * step);
        const float4 r3 = *reinterpret_cast<const float4*>(rp + 3 * step);
        process(s0, v0, r0, spl);
        process(s1, v1, r1, spl + step);
        process(s2, v2, r2, spl + 2 * step);
        process(s3, v3, r3, spl + 3 * step);
        spl += 4 * step; vp += 4 * step; rp += 4 * step;
    }
    for (; k < niter; ++k) {                    // generic-shape tail only
        const int    s0 = spl[0];
        const float4 v0 = *reinterpret_cast<const float4*>(vp);
        const float4 r0 = *reinterpret_cast<const float4*>(rp);
        process(s0, v0, r0, spl);
        spl += step; vp += step; rp += step;
    }

    // wave reduction (4 quantities)
    double acc_cnt = (double)cnt;
    #pragma unroll
    for (int off = 32; off > 0; off >>= 1) {
        acc_sq  += __shfl_down(acc_sq,  off);
        acc_cnt += __shfl_down(acc_cnt, off);
        acc_sd  += __shfl_down(acc_sd,  off);
        acc_sr  += __shfl_down(acc_sr,  off);
    }

    __shared__ double sm[4][4];
    if (lane == 0) {
        sm[0][wv] = acc_sq;
        sm[1][wv] = acc_cnt;
        sm[2][wv] = acc_sd;
        sm[3][wv] = acc_sr;
    }
    __syncthreads();
    if (threadIdx.x == 0) {
        part[0 * (size_t)nb + blockIdx.x] = sm[0][0] + sm[0][1] + sm[0][2] + sm[0][3];
        part[1 * (size_t)nb + blockIdx.x] = sm[1][0] + sm[1][1] + sm[1][2] + sm[1][3];
        part[2 * (size_t)nb + blockIdx.x] = sm[2][0] + sm[2][1] + sm[2][2] + sm[2][3];
        part[3 * (size_t)nb + blockIdx.x] = sm[3][0] + sm[3][1] + sm[3][2] + sm[3][3];
    }
}

// One block, 4 waves: wave c reduces component c over nb block-partials.
__global__ __launch_bounds__(256) void ac_mse_final(
    const double* __restrict__ part, float* __restrict__ out,
    int nb, double inv_n) {

    const int lane = threadIdx.x & 63;
    const int c = threadIdx.x >> 6;
    const double* p = part + (size_t)c * nb;

    double a0 = 0, a1 = 0, a2 = 0, a3 = 0;
    int b = lane;
    for (; b + 192 < nb; b += 256) {
        a0 += p[b]; a1 += p[b + 64]; a2 += p[b + 128]; a3 += p[b + 192];
    }
    for (; b < nb; b += 64) a0 += p[b];
    double a = (a0 + a1) + (a2 + a3);

    #pragma unroll
    for (int off = 32; off > 0; off >>= 1) a += __shfl_down(a, off);

    __shared__ double sm[4];
    if (lane == 0) sm[c] = a;
    __syncthreads();
    if (threadIdx.x == 0) {
        out[0] = (float)(sm[0] / sm[1]);            // loss
        out[1] = (float)(sm[2] * inv_n);            // mean(reward - value)
        out[2] = (float)(sm[3] * inv_n);            // mean(reward)
    }
}

extern "C" void kernel_launch(void* const* d_in, const int* in_sizes, int n_in,
                              void* d_out, int out_size, void* d_ws, size_t ws_size,
                              hipStream_t stream) {
    const int*   seq    = (const int*)d_in[0];
    const float* value  = (const float*)d_in[1];
    const float* reward = (const float*)d_in[2];
    float*  out = (float*)d_out;
    double* ws  = (double*)d_ws;

    const int S = 256;
    const long long total = (long long)in_sizes[0];
    const int B = (int)(total / S);

    int nb = 2048;   // 8192 waves -> 8 rows/wave at bench shape
    while ((size_t)nb * 4 * sizeof(double) > ws_size && nb > 1) nb >>= 1;

    ac_mse_reduce<<<nb, 256, 0, stream>>>(seq, value, reward, ws, B, nb);
    ac_mse_final<<<1, 256, 0, stream>>>(ws, out, nb, 1.0 / (double)total);
}